// Round 13
// baseline (177.679 us; speedup 1.0000x reference)
//
#include <hip/hip_runtime.h>
#include <math.h>

#define N_NODES 10000
#define N_EDGES 320000
#define D_IN    128
#define D2      256
#define HEADS   8
#define HID     32
#define D_OUT   64

typedef _Float16 h2   __attribute__((ext_vector_type(2)));
typedef _Float16 f16x8 __attribute__((ext_vector_type(8)));
typedef float    f32x4 __attribute__((ext_vector_type(4)));

__device__ __forceinline__ float fdot2(h2 a, h2 b, float c) {
#if __has_builtin(__builtin_amdgcn_fdot2)
    return __builtin_amdgcn_fdot2(a, b, c, false);
#else
    return fmaf((float)a.x, (float)b.x, fmaf((float)a.y, (float)b.y, c));
#endif
}
__device__ __forceinline__ h2 bch2(unsigned u) { return __builtin_bit_cast(h2, u); }
__device__ __forceinline__ unsigned packf(float a, float b) {
    h2 h = {(_Float16)a, (_Float16)b};
    return __builtin_bit_cast(unsigned, h);
}

// ---------------------------------------------------------------------------
// Zero the degree array
// ---------------------------------------------------------------------------
__global__ void zero_deg(int* __restrict__ deg) {
    const int i = blockIdx.x * 256 + threadIdx.x;
    if (i < N_NODES) deg[i] = 0;
}

// ---------------------------------------------------------------------------
// Fused prep: att fp16 conversion, W transpose->fp16 Wt[col][k], deg count.
// blocks: 0 att1 | 1 att2 | 2 att3 | [3,59) W transpose | [59, ...) deg count
// ---------------------------------------------------------------------------
__global__ void prep_all(const float* __restrict__ a1, unsigned* __restrict__ a1h,
                         const float* __restrict__ a2, unsigned* __restrict__ a2h,
                         const float* __restrict__ a3, unsigned* __restrict__ a3h,
                         const float* __restrict__ W1l, const float* __restrict__ W1r,
                         const float* __restrict__ W2l, const float* __restrict__ W2r,
                         const float* __restrict__ W3l, const float* __restrict__ W3r,
                         _Float16* __restrict__ T1l, _Float16* __restrict__ T1r,
                         _Float16* __restrict__ T2l, _Float16* __restrict__ T2r,
                         _Float16* __restrict__ T3l, _Float16* __restrict__ T3r,
                         const int* __restrict__ ei, int* __restrict__ deg) {
    const int b = blockIdx.x, t = threadIdx.x;
    if (b == 0) {
        if (t < 128) a1h[t] = packf(a1[2 * t], a1[2 * t + 1]);
    } else if (b == 1) {
        if (t < 128) a2h[t] = packf(a2[2 * t], a2[2 * t + 1]);
    } else if (b == 2) {
        if (t < 32) a3h[t] = packf(a3[2 * t], a3[2 * t + 1]);
    } else if (b < 59) {
        // 64x64 tile transpose W[K][M] fp32 -> Wt[M][K] fp16
        __shared__ float tl[64][65];
        const int wb = b - 3;
        const float* Wsrc; _Float16* Wdst; int K, M, tile;
        if (wb < 16)      { K = 128; M = 256; const bool r = wb >= 8;  Wsrc = r ? W1r : W1l; Wdst = r ? T1r : T1l; tile = wb & 7; }
        else if (wb < 48) { K = 256; M = 256; const bool r = wb >= 32; Wsrc = r ? W2r : W2l; Wdst = r ? T2r : T2l; tile = (wb - 16) & 15; }
        else              { K = 256; M = 64;  const bool r = wb >= 52; Wsrc = r ? W3r : W3l; Wdst = r ? T3r : T3l; tile = (wb - 48) & 3; }
        const int ktiles = K >> 6;
        const int k0 = (tile % ktiles) * 64, c0 = (tile / ktiles) * 64;
        const int rr = t >> 6, cc = t & 63;
        for (int i = 0; i < 64; i += 4)
            tl[i + rr][cc] = Wsrc[(size_t)(k0 + i + rr) * M + c0 + cc];
        __syncthreads();
        for (int i = 0; i < 64; i += 4)
            Wdst[(size_t)(c0 + i + rr) * K + k0 + cc] = (_Float16)tl[cc][i + rr];
    } else {
        const int e = (b - 59) * 256 + t;
        if (e < N_EDGES) atomicAdd(&deg[ei[N_EDGES + e]], 1);
    }
}

// ---------------------------------------------------------------------------
// MFMA dual GEMM: gl = A@Wl + bl, gr = A@Wr + br.
// A: fp16 k-pairs (AF32=false) or raw fp32 (AF32=true, converted in-stage).
// Wt*: [M][K] fp16 (transposed). 64x64 tile, 4 waves; mfma_f32_16x16x32_f16.
// ---------------------------------------------------------------------------
template<int K, bool HOUT, bool AF32>
__global__ __launch_bounds__(256) void gemm_dual_mfma(
        const void* __restrict__ Av,
        const _Float16* __restrict__ Wtl, const float* __restrict__ bl,
        const _Float16* __restrict__ Wtr, const float* __restrict__ br,
        void* __restrict__ glv, void* __restrict__ grv,
        int Mtot, int nrows) {
    constexpr int AS = K + 8;                 // padded A row stride (fp16)
    __shared__ __align__(16) _Float16 Asm[64 * AS];
    __shared__ __align__(16) _Float16 Wsm[2][64 * 40];  // [L/R][col][32k + 8 pad]

    const int t = threadIdx.x;
    const int wave = t >> 6, lane = t & 63;
    const int lrow = lane & 15, lgrp = lane >> 4;
    const int row0 = blockIdx.x * 64, col0 = blockIdx.y * 64;

    // ---- stage A (full K), zero-padded OOB rows ----
    if constexpr (AF32) {
        const float* Af = (const float*)Av;
        constexpr int CPR = K / 4;            // float4 chunks per row
        const int ar = t / CPR, ac = t % CPR;
        for (int i = 0; i < 64; i += 256 / CPR) {
            const int row = row0 + i + ar;
            float4 v = make_float4(0.f, 0.f, 0.f, 0.f);
            if (row < nrows) v = *reinterpret_cast<const float4*>(&Af[(size_t)row * K + ac * 4]);
            uint2 p;
            p.x = packf(v.x, v.y);
            p.y = packf(v.z, v.w);
            *reinterpret_cast<uint2*>(&Asm[(i + ar) * AS + ac * 4]) = p;
        }
    } else {
        const unsigned* Ah = (const unsigned*)Av;
        constexpr int CPR = K / 8;            // uint4 chunks per row
        const int ar = t / CPR, ac = t % CPR;
        for (int i = 0; i < 64; i += 256 / CPR) {
            const int row = row0 + i + ar;
            uint4 v = make_uint4(0u, 0u, 0u, 0u);
            if (row < nrows) v = *reinterpret_cast<const uint4*>(&Ah[(size_t)row * (K / 2) + ac * 4]);
            *reinterpret_cast<uint4*>(&Asm[(i + ar) * AS + ac * 8]) = v;
        }
    }

    f32x4 accL[4], accR[4];
#pragma unroll
    for (int cf = 0; cf < 4; ++cf) { accL[cf] = (f32x4)0.0f; accR[cf] = (f32x4)0.0f; }

    const int wcol = t >> 2, wch = t & 3;     // W staging map: 64 cols x 4 chunks

    for (int ks = 0; ks < K / 32; ++ks) {
        __syncthreads();
        {
            const uint4 vl = *reinterpret_cast<const uint4*>(&Wtl[(size_t)(col0 + wcol) * K + ks * 32 + wch * 8]);
            const uint4 vr = *reinterpret_cast<const uint4*>(&Wtr[(size_t)(col0 + wcol) * K + ks * 32 + wch * 8]);
            *reinterpret_cast<uint4*>(&Wsm[0][wcol * 40 + wch * 8]) = vl;
            *reinterpret_cast<uint4*>(&Wsm[1][wcol * 40 + wch * 8]) = vr;
        }
        __syncthreads();

        const f16x8 a = *reinterpret_cast<const f16x8*>(
            &Asm[(wave * 16 + lrow) * AS + ks * 32 + lgrp * 8]);
#pragma unroll
        for (int cf = 0; cf < 4; ++cf) {
            const f16x8 b_l = *reinterpret_cast<const f16x8*>(&Wsm[0][(cf * 16 + lrow) * 40 + lgrp * 8]);
            const f16x8 b_r = *reinterpret_cast<const f16x8*>(&Wsm[1][(cf * 16 + lrow) * 40 + lgrp * 8]);
            accL[cf] = __builtin_amdgcn_mfma_f32_16x16x32_f16(a, b_l, accL[cf], 0, 0, 0);
            accR[cf] = __builtin_amdgcn_mfma_f32_16x16x32_f16(a, b_r, accR[cf], 0, 0, 0);
        }
    }

    // ---- epilogue: D col=lane&15, row=(lane>>4)*4+reg ----
#pragma unroll
    for (int cf = 0; cf < 4; ++cf) {
        const int col = col0 + cf * 16 + lrow;
        const float bll = bl[col], brr = br[col];
#pragma unroll
        for (int r = 0; r < 4; ++r) {
            const int row = row0 + wave * 16 + lgrp * 4 + r;
            if (row < nrows) {
                if constexpr (HOUT) {
                    _Float16* glh = (_Float16*)glv;
                    _Float16* grh = (_Float16*)grv;
                    glh[(size_t)row * Mtot + col] = (_Float16)(accL[cf][r] + bll);
                    grh[(size_t)row * Mtot + col] = (_Float16)(accR[cf][r] + brr);
                } else {
                    float* glf = (float*)glv;
                    float* grf = (float*)grv;
                    glf[(size_t)row * Mtot + col] = accL[cf][r] + bll;
                    grf[(size_t)row * Mtot + col] = accR[cf][r] + brr;
                }
            }
        }
    }
}

// ---------------------------------------------------------------------------
// CSR build: single-block scan -> scatter src ids by dst.
// ---------------------------------------------------------------------------
__global__ void scan_rowptr(const int* __restrict__ deg,
                            int* __restrict__ row_ptr, int* __restrict__ cursor) {
    __shared__ int part[1024];
    const int t = threadIdx.x;
    const int base = t * 10;
    int loc[10];
    int s = 0;
#pragma unroll
    for (int i = 0; i < 10; ++i) {
        const int v = (base + i < N_NODES) ? deg[base + i] : 0;
        loc[i] = s; s += v;
    }
    part[t] = s;
    __syncthreads();
    for (int d = 1; d < 1024; d <<= 1) {
        const int v = (t >= d) ? part[t - d] : 0;
        __syncthreads();
        part[t] += v;
        __syncthreads();
    }
    const int off = (t > 0) ? part[t - 1] : 0;
#pragma unroll
    for (int i = 0; i < 10; ++i) {
        const int idx = base + i;
        if (idx < N_NODES) {
            const int r = off + loc[i];
            row_ptr[idx] = r; cursor[idx] = r;
        }
    }
    if (t == 0) row_ptr[N_NODES] = N_EDGES;
}

__global__ void scatter_edges(const int* __restrict__ ei, int* __restrict__ cursor,
                              int* __restrict__ esrc) {
    const int e = blockIdx.x * blockDim.x + threadIdx.x;
    if (e < N_EDGES) {
        const int pos = atomicAdd(&cursor[ei[N_EDGES + e]], 1);
        esrc[pos] = ei[e];
    }
}

// ---------------------------------------------------------------------------
// Split-wave fused GATv2, M=256 H=8 C=32, fp16 rows, elu output (fp16).
// 2 edges per iteration (32 lanes each, uint4 gathers), no-max softmax,
// depth-4 rotating prefetch. 128-THREAD BLOCKS (2 nodes/block): finer
// workgroup retirement -> more resident waves -> more outstanding gathers.
// ---------------------------------------------------------------------------
__global__ __launch_bounds__(128) void gat_wave_h2(
        const int* __restrict__ row_ptr, const int* __restrict__ esrc,
        const unsigned* __restrict__ gl, const unsigned* __restrict__ gr,
        const unsigned* __restrict__ atth, const float* __restrict__ bias,
        unsigned* __restrict__ hout) {
    constexpr int MU = D2 / 2;                    // 128 uints per row
    const int wid  = threadIdx.x >> 6;
    const int lane = threadIdx.x & 63;
    const int half = lane >> 5;
    const int sub  = lane & 31;
    const int n = blockIdx.x * 2 + wid;
    if (n >= N_NODES) return;
    const int u4 = sub * 4;
    const int c0 = sub * 8;

    h2 grn[4], av[4];
    {
        const uint4 u = *reinterpret_cast<const uint4*>(&gr[(size_t)n * MU + u4]);
        grn[0] = bch2(u.x); grn[1] = bch2(u.y); grn[2] = bch2(u.z); grn[3] = bch2(u.w);
        const uint4 a = *reinterpret_cast<const uint4*>(&atth[u4]);
        av[0] = bch2(a.x); av[1] = bch2(a.y); av[2] = bch2(a.z); av[3] = bch2(a.w);
    }
    const h2 hz = {(_Float16)0.f, (_Float16)0.f};
    const h2 hp = {(_Float16)0.2f, (_Float16)0.2f};

    float acc[8] = {0.f, 0.f, 0.f, 0.f, 0.f, 0.f, 0.f, 0.f};
    float denom = 0.0f;

    const int beg = row_ptr[n], end = row_ptr[n + 1];

    for (int base = beg; base < end; base += 64) {
        const int len = min(64, end - base);
        const int npairs = (len + 1) >> 1;
        const int myid = (base + lane < end) ? esrc[base + lane] : 0;

#define LOADP(k) (*reinterpret_cast<const uint4*>(&gl[(size_t)__shfl(myid, 2 * (k) + half) * MU + u4]))
        uint4 g0 = LOADP(0);
        uint4 g1 = (npairs > 1) ? LOADP(1) : g0;
        uint4 g2 = (npairs > 2) ? LOADP(2) : g0;
        uint4 g3 = (npairs > 3) ? LOADP(3) : g0;

        for (int i = 0; i < npairs; ++i) {
            const uint4 nxt = (i + 4 < npairs) ? LOADP(i + 4) : g0;

            const h2 G[4] = {bch2(g0.x), bch2(g0.y), bch2(g0.z), bch2(g0.w)};
            float s = 0.0f;
#pragma unroll
            for (int q = 0; q < 4; ++q) {
                const h2 v = G[q] + grn[q];
                const h2 lr = __builtin_elementwise_min(v, hz) * hp +
                              __builtin_elementwise_max(v, hz);
                s = fdot2(lr, av[q], s);
            }
            s += __shfl_xor(s, 1, 64);
            s += __shfl_xor(s, 2, 64);
            s = ((2 * i + half) < len) ? s : -INFINITY;   // masked edge -> exp = 0

            const float e1 = __expf(s);
            denom += e1;
#pragma unroll
            for (int q = 0; q < 4; ++q) {
                acc[2 * q]     = fmaf(e1, (float)G[q].x, acc[2 * q]);
                acc[2 * q + 1] = fmaf(e1, (float)G[q].y, acc[2 * q + 1]);
            }
            g0 = g1; g1 = g2; g2 = g3; g3 = nxt;
        }
#undef LOADP
    }

    denom += __shfl_xor(denom, 32, 64);
#pragma unroll
    for (int v2 = 0; v2 < 8; ++v2) acc[v2] += __shfl_xor(acc[v2], 32, 64);

    if (half == 0) {
        const float inv = 1.0f / (denom + 1e-16f);
        const float4 b0 = *reinterpret_cast<const float4*>(&bias[c0]);
        const float4 b1 = *reinterpret_cast<const float4*>(&bias[c0 + 4]);
        const float bb[8] = {b0.x, b0.y, b0.z, b0.w, b1.x, b1.y, b1.z, b1.w};
        float r[8];
#pragma unroll
        for (int v2 = 0; v2 < 8; ++v2) {
            float val = acc[v2] * inv + bb[v2];
            r[v2] = val > 0.0f ? val : expm1f(val);  // elu
        }
        uint4 o;
        o.x = packf(r[0], r[1]); o.y = packf(r[2], r[3]);
        o.z = packf(r[4], r[5]); o.w = packf(r[6], r[7]);
        *reinterpret_cast<uint4*>(&hout[(size_t)n * MU + u4]) = o;
    }
}

// ---------------------------------------------------------------------------
// Grouped fused GATv2 for layer 3: M=64, H=1, C=64, fp16 rows, sigmoid->fp32.
// 16 lanes per node (uint2 = 4ch/lane), 128-thread blocks (8 nodes/block),
// depth-6 prefetch.
// ---------------------------------------------------------------------------
__global__ __launch_bounds__(128) void gat_group3h(
        const int* __restrict__ row_ptr, const int* __restrict__ esrc,
        const unsigned* __restrict__ gl, const unsigned* __restrict__ gr,
        const unsigned* __restrict__ atth, const float* __restrict__ bias,
        float* __restrict__ out) {
    constexpr int MU = D_OUT / 2;                // 32 uints per row
    const int wid  = threadIdx.x >> 6;
    const int lane = threadIdx.x & 63;
    const int g    = lane >> 4;
    const int sub  = lane & 15;
    const int n = blockIdx.x * 8 + wid * 4 + g;
    const bool nvalid = (n < N_NODES);
    const int u2 = sub * 2, c0 = sub * 4;

    h2 grn0, grn1, a0, a1;
    {
        const uint2 u = *reinterpret_cast<const uint2*>(&gr[(size_t)(nvalid ? n : 0) * MU + u2]);
        grn0 = bch2(u.x); grn1 = bch2(u.y);
        const uint2 au = *reinterpret_cast<const uint2*>(&atth[u2]);
        a0 = bch2(au.x); a1 = bch2(au.y);
    }
    const h2 hz = {(_Float16)0.f, (_Float16)0.f};
    const h2 hp = {(_Float16)0.2f, (_Float16)0.2f};

    float acc[4] = {0.f, 0.f, 0.f, 0.f};
    float denom = 0.0f;

    const int beg = nvalid ? row_ptr[n] : 0;
    const int deg = nvalid ? (row_ptr[n + 1] - beg) : 0;

    for (int off = 0; __any(off < deg); off += 16) {
        const int myid = (off + sub < deg) ? esrc[beg + off + sub] : 0;

#define GLD(j) (*reinterpret_cast<const uint2*>(&gl[(size_t)__shfl(myid, (g << 4) + (j)) * MU + u2]))
        uint2 r0 = GLD(0), r1 = GLD(1), r2 = GLD(2), r3 = GLD(3), r4 = GLD(4), r5 = GLD(5);
#pragma unroll
        for (int j = 0; j < 16; ++j) {
            const uint2 nxt = (j + 6 < 16) ? GLD(j + 6) : r0;
            const h2 G0 = bch2(r0.x), G1 = bch2(r0.y);
            const h2 v0 = G0 + grn0, v1 = G1 + grn1;
            const h2 lr0 = __builtin_elementwise_min(v0, hz) * hp + __builtin_elementwise_max(v0, hz);
            const h2 lr1 = __builtin_elementwise_min(v1, hz) * hp + __builtin_elementwise_max(v1, hz);
            float s = fdot2(lr1, a1, fdot2(lr0, a0, 0.0f));
            s += __shfl_xor(s, 1, 64);
            s += __shfl_xor(s, 2, 64);
            s += __shfl_xor(s, 4, 64);
            s += __shfl_xor(s, 8, 64);
            s = ((off + j) < deg) ? s : -INFINITY;

            const float e1 = __expf(s);
            denom += e1;
            acc[0] = fmaf(e1, (float)G0.x, acc[0]);
            acc[1] = fmaf(e1, (float)G0.y, acc[1]);
            acc[2] = fmaf(e1, (float)G1.x, acc[2]);
            acc[3] = fmaf(e1, (float)G1.y, acc[3]);
            r0 = r1; r1 = r2; r2 = r3; r3 = r4; r4 = r5; r5 = nxt;
        }
#undef GLD
    }

    if (nvalid) {
        const float inv = 1.0f / (denom + 1e-16f);
        const float4 b4 = *reinterpret_cast<const float4*>(&bias[c0]);
        float4 r;
        r.x = 1.0f / (1.0f + __expf(-(acc[0] * inv + b4.x)));
        r.y = 1.0f / (1.0f + __expf(-(acc[1] * inv + b4.y)));
        r.z = 1.0f / (1.0f + __expf(-(acc[2] * inv + b4.z)));
        r.w = 1.0f / (1.0f + __expf(-(acc[3] * inv + b4.w)));
        *reinterpret_cast<float4*>(&out[(size_t)n * D_OUT + c0]) = r;
    }
}

extern "C" void kernel_launch(void* const* d_in, const int* in_sizes, int n_in,
                              void* d_out, int out_size, void* d_ws, size_t ws_size,
                              hipStream_t stream) {
    const float* x    = (const float*)d_in[0];
    const int*   ei   = (const int*)  d_in[1];
    const float* Wl1  = (const float*)d_in[2];
    const float* bl1  = (const float*)d_in[3];
    const float* Wr1  = (const float*)d_in[4];
    const float* br1  = (const float*)d_in[5];
    const float* att1 = (const float*)d_in[6];
    const float* bi1  = (const float*)d_in[7];
    const float* Wl2  = (const float*)d_in[8];
    const float* bl2  = (const float*)d_in[9];
    const float* Wr2  = (const float*)d_in[10];
    const float* br2  = (const float*)d_in[11];
    const float* att2 = (const float*)d_in[12];
    const float* bi2  = (const float*)d_in[13];
    const float* Wl3  = (const float*)d_in[14];
    const float* bl3  = (const float*)d_in[15];
    const float* Wr3  = (const float*)d_in[16];
    const float* br3  = (const float*)d_in[17];
    const float* att3 = (const float*)d_in[18];
    const float* bi3  = (const float*)d_in[19];

    float* out = (float*)d_out;

    // ---- workspace layout (uints) ----
    unsigned* ws   = (unsigned*)d_ws;
    unsigned* gl16 = ws;                               // N*128
    unsigned* gr16 = gl16 + (size_t)N_NODES * 128;     // N*128
    unsigned* h16  = gr16 + (size_t)N_NODES * 128;     // N*128
    unsigned* gl3  = h16  + (size_t)N_NODES * 128;     // N*32 (fp16 rows, layer 3)
    unsigned* gr3  = gl3  + (size_t)N_NODES * 32;      // N*32
    _Float16* T1l  = (_Float16*)(gr3 + (size_t)N_NODES * 32); // 32768 f16
    _Float16* T1r  = T1l + 32768;
    _Float16* T2l  = T1r + 32768;                      // 65536 f16
    _Float16* T2r  = T2l + 65536;
    _Float16* T3l  = T2r + 65536;                      // 16384 f16
    _Float16* T3r  = T3l + 16384;
    unsigned* ath1 = (unsigned*)(T3r + 16384);         // 128
    unsigned* ath2 = ath1 + 128;
    unsigned* ath3 = ath2 + 128;                       // 32
    int* deg     = (int*)(ath3 + 32);                  // N
    int* row_ptr = deg + N_NODES;                      // N+1
    int* cursor  = row_ptr + N_NODES + 1;              // N
    int* esrc    = cursor + N_NODES;                   // E

    // ---- prep: zero deg; conversions + W transpose + degree count; CSR ----
    zero_deg<<<(N_NODES + 255) / 256, 256, 0, stream>>>(deg);
    prep_all<<<59 + (N_EDGES + 255) / 256, 256, 0, stream>>>(
        att1, ath1, att2, ath2, att3, ath3,
        Wl1, Wr1, Wl2, Wr2, Wl3, Wr3,
        T1l, T1r, T2l, T2r, T3l, T3r,
        ei, deg);
    scan_rowptr<<<1, 1024, 0, stream>>>(deg, row_ptr, cursor);
    scatter_edges<<<(N_EDGES + 255) / 256, 256, 0, stream>>>(ei, cursor, esrc);

    const int RT64 = (N_NODES + 63) / 64;              // 157

    // ---- Layer 1: 128 -> 8x32, elu (A read as fp32 directly) ----
    gemm_dual_mfma<D_IN, true, true><<<dim3(RT64, 4), 256, 0, stream>>>(
        x, T1l, bl1, T1r, br1, gl16, gr16, D2, N_NODES);
    gat_wave_h2<<<(N_NODES + 1) / 2, 128, 0, stream>>>(
        row_ptr, esrc, gl16, gr16, ath1, bi1, h16);

    // ---- Layer 2: 256 -> 8x32, elu ----
    gemm_dual_mfma<D2, true, false><<<dim3(RT64, 4), 256, 0, stream>>>(
        h16, T2l, bl2, T2r, br2, gl16, gr16, D2, N_NODES);
    gat_wave_h2<<<(N_NODES + 1) / 2, 128, 0, stream>>>(
        row_ptr, esrc, gl16, gr16, ath2, bi2, h16);

    // ---- Layer 3: 256 -> 64, 1 head, sigmoid (fp16 rows) ----
    gemm_dual_mfma<D2, true, false><<<dim3(RT64, 1), 256, 0, stream>>>(
        h16, T3l, bl3, T3r, br3, gl3, gr3, D_OUT, N_NODES);
    gat_group3h<<<(N_NODES + 7) / 8, 128, 0, stream>>>(
        row_ptr, esrc, gl3, gr3, ath3, bi3, out);
}

// Round 14
// 175.654 us; speedup vs baseline: 1.0115x; 1.0115x over previous
//
#include <hip/hip_runtime.h>
#include <math.h>

#define N_NODES 10000
#define N_EDGES 320000
#define D_IN    128
#define D2      256
#define HEADS   8
#define HID     32
#define D_OUT   64
#define LOG2E   1.4426950408889634f

typedef _Float16 h2   __attribute__((ext_vector_type(2)));
typedef _Float16 f16x8 __attribute__((ext_vector_type(8)));
typedef float    f32x4 __attribute__((ext_vector_type(4)));
typedef float    f32x2 __attribute__((ext_vector_type(2)));

__device__ __forceinline__ float fdot2(h2 a, h2 b, float c) {
#if __has_builtin(__builtin_amdgcn_fdot2)
    return __builtin_amdgcn_fdot2(a, b, c, false);
#else
    return fmaf((float)a.x, (float)b.x, fmaf((float)a.y, (float)b.y, c));
#endif
}
__device__ __forceinline__ float fexp2(float x) {
#if __has_builtin(__builtin_amdgcn_exp2f)
    return __builtin_amdgcn_exp2f(x);
#else
    return exp2f(x);
#endif
}
__device__ __forceinline__ h2 bch2(unsigned u) { return __builtin_bit_cast(h2, u); }
__device__ __forceinline__ unsigned packf(float a, float b) {
    h2 h = {(_Float16)a, (_Float16)b};
    return __builtin_bit_cast(unsigned, h);
}

// ---------------------------------------------------------------------------
// Zero the degree array
// ---------------------------------------------------------------------------
__global__ void zero_deg(int* __restrict__ deg) {
    const int i = blockIdx.x * 256 + threadIdx.x;
    if (i < N_NODES) deg[i] = 0;
}

// ---------------------------------------------------------------------------
// Fused prep: att fp16 conversion (PRE-SCALED by log2e so exp -> exp2),
// W transpose->fp16 Wt[col][k], deg count.
// blocks: 0 att1 | 1 att2 | 2 att3 | [3,59) W transpose | [59, ...) deg count
// ---------------------------------------------------------------------------
__global__ void prep_all(const float* __restrict__ a1, unsigned* __restrict__ a1h,
                         const float* __restrict__ a2, unsigned* __restrict__ a2h,
                         const float* __restrict__ a3, unsigned* __restrict__ a3h,
                         const float* __restrict__ W1l, const float* __restrict__ W1r,
                         const float* __restrict__ W2l, const float* __restrict__ W2r,
                         const float* __restrict__ W3l, const float* __restrict__ W3r,
                         _Float16* __restrict__ T1l, _Float16* __restrict__ T1r,
                         _Float16* __restrict__ T2l, _Float16* __restrict__ T2r,
                         _Float16* __restrict__ T3l, _Float16* __restrict__ T3r,
                         const int* __restrict__ ei, int* __restrict__ deg) {
    const int b = blockIdx.x, t = threadIdx.x;
    if (b == 0) {
        if (t < 128) a1h[t] = packf(a1[2 * t] * LOG2E, a1[2 * t + 1] * LOG2E);
    } else if (b == 1) {
        if (t < 128) a2h[t] = packf(a2[2 * t] * LOG2E, a2[2 * t + 1] * LOG2E);
    } else if (b == 2) {
        if (t < 32) a3h[t] = packf(a3[2 * t] * LOG2E, a3[2 * t + 1] * LOG2E);
    } else if (b < 59) {
        // 64x64 tile transpose W[K][M] fp32 -> Wt[M][K] fp16
        __shared__ float tl[64][65];
        const int wb = b - 3;
        const float* Wsrc; _Float16* Wdst; int K, M, tile;
        if (wb < 16)      { K = 128; M = 256; const bool r = wb >= 8;  Wsrc = r ? W1r : W1l; Wdst = r ? T1r : T1l; tile = wb & 7; }
        else if (wb < 48) { K = 256; M = 256; const bool r = wb >= 32; Wsrc = r ? W2r : W2l; Wdst = r ? T2r : T2l; tile = (wb - 16) & 15; }
        else              { K = 256; M = 64;  const bool r = wb >= 52; Wsrc = r ? W3r : W3l; Wdst = r ? T3r : T3l; tile = (wb - 48) & 3; }
        const int ktiles = K >> 6;
        const int k0 = (tile % ktiles) * 64, c0 = (tile / ktiles) * 64;
        const int rr = t >> 6, cc = t & 63;
        for (int i = 0; i < 64; i += 4)
            tl[i + rr][cc] = Wsrc[(size_t)(k0 + i + rr) * M + c0 + cc];
        __syncthreads();
        for (int i = 0; i < 64; i += 4)
            Wdst[(size_t)(c0 + i + rr) * K + k0 + cc] = (_Float16)tl[cc][i + rr];
    } else {
        const int e = (b - 59) * 256 + t;
        if (e < N_EDGES) atomicAdd(&deg[ei[N_EDGES + e]], 1);
    }
}

// ---------------------------------------------------------------------------
// MFMA dual GEMM: gl = A@Wl + bl, gr = A@Wr + br.
// A: fp16 k-pairs (AF32=false) or raw fp32 (AF32=true, converted in-stage).
// Wt*: [M][K] fp16 (transposed). 64x64 tile, 4 waves; mfma_f32_16x16x32_f16.
// ---------------------------------------------------------------------------
template<int K, bool HOUT, bool AF32>
__global__ __launch_bounds__(256) void gemm_dual_mfma(
        const void* __restrict__ Av,
        const _Float16* __restrict__ Wtl, const float* __restrict__ bl,
        const _Float16* __restrict__ Wtr, const float* __restrict__ br,
        void* __restrict__ glv, void* __restrict__ grv,
        int Mtot, int nrows) {
    constexpr int AS = K + 8;                 // padded A row stride (fp16)
    __shared__ __align__(16) _Float16 Asm[64 * AS];
    __shared__ __align__(16) _Float16 Wsm[2][64 * 40];  // [L/R][col][32k + 8 pad]

    const int t = threadIdx.x;
    const int wave = t >> 6, lane = t & 63;
    const int lrow = lane & 15, lgrp = lane >> 4;
    const int row0 = blockIdx.x * 64, col0 = blockIdx.y * 64;

    // ---- stage A (full K), zero-padded OOB rows ----
    if constexpr (AF32) {
        const float* Af = (const float*)Av;
        constexpr int CPR = K / 4;            // float4 chunks per row
        const int ar = t / CPR, ac = t % CPR;
        for (int i = 0; i < 64; i += 256 / CPR) {
            const int row = row0 + i + ar;
            float4 v = make_float4(0.f, 0.f, 0.f, 0.f);
            if (row < nrows) v = *reinterpret_cast<const float4*>(&Af[(size_t)row * K + ac * 4]);
            uint2 p;
            p.x = packf(v.x, v.y);
            p.y = packf(v.z, v.w);
            *reinterpret_cast<uint2*>(&Asm[(i + ar) * AS + ac * 4]) = p;
        }
    } else {
        const unsigned* Ah = (const unsigned*)Av;
        constexpr int CPR = K / 8;            // uint4 chunks per row
        const int ar = t / CPR, ac = t % CPR;
        for (int i = 0; i < 64; i += 256 / CPR) {
            const int row = row0 + i + ar;
            uint4 v = make_uint4(0u, 0u, 0u, 0u);
            if (row < nrows) v = *reinterpret_cast<const uint4*>(&Ah[(size_t)row * (K / 2) + ac * 4]);
            *reinterpret_cast<uint4*>(&Asm[(i + ar) * AS + ac * 8]) = v;
        }
    }

    f32x4 accL[4], accR[4];
#pragma unroll
    for (int cf = 0; cf < 4; ++cf) { accL[cf] = (f32x4)0.0f; accR[cf] = (f32x4)0.0f; }

    const int wcol = t >> 2, wch = t & 3;     // W staging map: 64 cols x 4 chunks

    for (int ks = 0; ks < K / 32; ++ks) {
        __syncthreads();
        {
            const uint4 vl = *reinterpret_cast<const uint4*>(&Wtl[(size_t)(col0 + wcol) * K + ks * 32 + wch * 8]);
            const uint4 vr = *reinterpret_cast<const uint4*>(&Wtr[(size_t)(col0 + wcol) * K + ks * 32 + wch * 8]);
            *reinterpret_cast<uint4*>(&Wsm[0][wcol * 40 + wch * 8]) = vl;
            *reinterpret_cast<uint4*>(&Wsm[1][wcol * 40 + wch * 8]) = vr;
        }
        __syncthreads();

        const f16x8 a = *reinterpret_cast<const f16x8*>(
            &Asm[(wave * 16 + lrow) * AS + ks * 32 + lgrp * 8]);
#pragma unroll
        for (int cf = 0; cf < 4; ++cf) {
            const f16x8 b_l = *reinterpret_cast<const f16x8*>(&Wsm[0][(cf * 16 + lrow) * 40 + lgrp * 8]);
            const f16x8 b_r = *reinterpret_cast<const f16x8*>(&Wsm[1][(cf * 16 + lrow) * 40 + lgrp * 8]);
            accL[cf] = __builtin_amdgcn_mfma_f32_16x16x32_f16(a, b_l, accL[cf], 0, 0, 0);
            accR[cf] = __builtin_amdgcn_mfma_f32_16x16x32_f16(a, b_r, accR[cf], 0, 0, 0);
        }
    }

    // ---- epilogue: D col=lane&15, row=(lane>>4)*4+reg ----
#pragma unroll
    for (int cf = 0; cf < 4; ++cf) {
        const int col = col0 + cf * 16 + lrow;
        const float bll = bl[col], brr = br[col];
#pragma unroll
        for (int r = 0; r < 4; ++r) {
            const int row = row0 + wave * 16 + lgrp * 4 + r;
            if (row < nrows) {
                if constexpr (HOUT) {
                    _Float16* glh = (_Float16*)glv;
                    _Float16* grh = (_Float16*)grv;
                    glh[(size_t)row * Mtot + col] = (_Float16)(accL[cf][r] + bll);
                    grh[(size_t)row * Mtot + col] = (_Float16)(accR[cf][r] + brr);
                } else {
                    float* glf = (float*)glv;
                    float* grf = (float*)grv;
                    glf[(size_t)row * Mtot + col] = accL[cf][r] + bll;
                    grf[(size_t)row * Mtot + col] = accR[cf][r] + brr;
                }
            }
        }
    }
}

// ---------------------------------------------------------------------------
// CSR build: single-block scan -> scatter src ids by dst.
// ---------------------------------------------------------------------------
__global__ void scan_rowptr(const int* __restrict__ deg,
                            int* __restrict__ row_ptr, int* __restrict__ cursor) {
    __shared__ int part[1024];
    const int t = threadIdx.x;
    const int base = t * 10;
    int loc[10];
    int s = 0;
#pragma unroll
    for (int i = 0; i < 10; ++i) {
        const int v = (base + i < N_NODES) ? deg[base + i] : 0;
        loc[i] = s; s += v;
    }
    part[t] = s;
    __syncthreads();
    for (int d = 1; d < 1024; d <<= 1) {
        const int v = (t >= d) ? part[t - d] : 0;
        __syncthreads();
        part[t] += v;
        __syncthreads();
    }
    const int off = (t > 0) ? part[t - 1] : 0;
#pragma unroll
    for (int i = 0; i < 10; ++i) {
        const int idx = base + i;
        if (idx < N_NODES) {
            const int r = off + loc[i];
            row_ptr[idx] = r; cursor[idx] = r;
        }
    }
    if (t == 0) row_ptr[N_NODES] = N_EDGES;
}

__global__ void scatter_edges(const int* __restrict__ ei, int* __restrict__ cursor,
                              int* __restrict__ esrc) {
    const int e = blockIdx.x * blockDim.x + threadIdx.x;
    if (e < N_EDGES) {
        const int pos = atomicAdd(&cursor[ei[N_EDGES + e]], 1);
        esrc[pos] = ei[e];
    }
}

// ---------------------------------------------------------------------------
// Split-wave fused GATv2, M=256 H=8 C=32, fp16 rows, elu output (fp16).
// 2 edges per iteration (32 lanes each, uint4 gathers), no-max softmax
// (att pre-scaled by log2e -> exp2 single-instr), pk_fma leakyrelu,
// packed f32x2 accumulate, depth-4 rotating prefetch.
// ---------------------------------------------------------------------------
__global__ __launch_bounds__(256) void gat_wave_h2(
        const int* __restrict__ row_ptr, const int* __restrict__ esrc,
        const unsigned* __restrict__ gl, const unsigned* __restrict__ gr,
        const unsigned* __restrict__ atth, const float* __restrict__ bias,
        unsigned* __restrict__ hout) {
    constexpr int MU = D2 / 2;                    // 128 uints per row
    const int wid  = threadIdx.x >> 6;
    const int lane = threadIdx.x & 63;
    const int half = lane >> 5;
    const int sub  = lane & 31;
    const int n = blockIdx.x * 4 + wid;
    if (n >= N_NODES) return;
    const int u4 = sub * 4;
    const int c0 = sub * 8;

    h2 grn[4], av[4];
    {
        const uint4 u = *reinterpret_cast<const uint4*>(&gr[(size_t)n * MU + u4]);
        grn[0] = bch2(u.x); grn[1] = bch2(u.y); grn[2] = bch2(u.z); grn[3] = bch2(u.w);
        const uint4 a = *reinterpret_cast<const uint4*>(&atth[u4]);
        av[0] = bch2(a.x); av[1] = bch2(a.y); av[2] = bch2(a.z); av[3] = bch2(a.w);
    }
    const h2 hz = {(_Float16)0.f, (_Float16)0.f};
    const h2 hp = {(_Float16)0.2f, (_Float16)0.2f};

    f32x2 accp[4];
#pragma unroll
    for (int q = 0; q < 4; ++q) accp[q] = (f32x2)0.0f;
    float denom = 0.0f;

    const int beg = row_ptr[n], end = row_ptr[n + 1];

    for (int base = beg; base < end; base += 64) {
        const int len = min(64, end - base);
        const int npairs = (len + 1) >> 1;
        const int myid = (base + lane < end) ? esrc[base + lane] : 0;

#define LOADP(k) (*reinterpret_cast<const uint4*>(&gl[(size_t)__shfl(myid, 2 * (k) + half) * MU + u4]))
        uint4 g0 = LOADP(0);
        uint4 g1 = (npairs > 1) ? LOADP(1) : g0;
        uint4 g2 = (npairs > 2) ? LOADP(2) : g0;
        uint4 g3 = (npairs > 3) ? LOADP(3) : g0;

        for (int i = 0; i < npairs; ++i) {
            const uint4 nxt = (i + 4 < npairs) ? LOADP(i + 4) : g0;

            const h2 G[4] = {bch2(g0.x), bch2(g0.y), bch2(g0.z), bch2(g0.w)};
            float s = 0.0f;
#pragma unroll
            for (int q = 0; q < 4; ++q) {
                const h2 v = G[q] + grn[q];
                const h2 lr = __builtin_elementwise_fma(
                    __builtin_elementwise_min(v, hz), hp,
                    __builtin_elementwise_max(v, hz));
                s = fdot2(lr, av[q], s);
            }
            s += __shfl_xor(s, 1, 64);
            s += __shfl_xor(s, 2, 64);
            s = ((2 * i + half) < len) ? s : -INFINITY;   // masked edge -> exp2 = 0

            const float e1 = fexp2(s);                    // att pre-scaled: == e^score
            denom += e1;
            const f32x2 e2 = {e1, e1};
#pragma unroll
            for (int q = 0; q < 4; ++q) {
                const f32x2 gf = {(float)G[q].x, (float)G[q].y};
                accp[q] = __builtin_elementwise_fma(gf, e2, accp[q]);
            }
            g0 = g1; g1 = g2; g2 = g3; g3 = nxt;
        }
#undef LOADP
    }

    denom += __shfl_xor(denom, 32, 64);
#pragma unroll
    for (int q = 0; q < 4; ++q) {
        accp[q].x += __shfl_xor(accp[q].x, 32, 64);
        accp[q].y += __shfl_xor(accp[q].y, 32, 64);
    }

    if (half == 0) {
        const float inv = 1.0f / (denom + 1e-16f);
        const float4 b0 = *reinterpret_cast<const float4*>(&bias[c0]);
        const float4 b1 = *reinterpret_cast<const float4*>(&bias[c0 + 4]);
        const float bb[8] = {b0.x, b0.y, b0.z, b0.w, b1.x, b1.y, b1.z, b1.w};
        float r[8];
#pragma unroll
        for (int q = 0; q < 4; ++q) {
            float v0 = accp[q].x * inv + bb[2 * q];
            float v1 = accp[q].y * inv + bb[2 * q + 1];
            r[2 * q]     = v0 > 0.0f ? v0 : expm1f(v0);   // elu
            r[2 * q + 1] = v1 > 0.0f ? v1 : expm1f(v1);
        }
        uint4 o;
        o.x = packf(r[0], r[1]); o.y = packf(r[2], r[3]);
        o.z = packf(r[4], r[5]); o.w = packf(r[6], r[7]);
        *reinterpret_cast<uint4*>(&hout[(size_t)n * MU + u4]) = o;
    }
}

// ---------------------------------------------------------------------------
// Grouped fused GATv2 for layer 3: M=64, H=1, C=64, fp16 rows, sigmoid->fp32.
// 16 lanes per node (uint2 = 4ch/lane), 4 nodes per wave, depth-6 prefetch.
// Same VALU shavings: fma-leakyrelu, exp2, packed acc.
// ---------------------------------------------------------------------------
__global__ __launch_bounds__(256) void gat_group3h(
        const int* __restrict__ row_ptr, const int* __restrict__ esrc,
        const unsigned* __restrict__ gl, const unsigned* __restrict__ gr,
        const unsigned* __restrict__ atth, const float* __restrict__ bias,
        float* __restrict__ out) {
    constexpr int MU = D_OUT / 2;                // 32 uints per row
    const int wid  = threadIdx.x >> 6;
    const int lane = threadIdx.x & 63;
    const int g    = lane >> 4;
    const int sub  = lane & 15;
    const int n = blockIdx.x * 16 + wid * 4 + g;
    const bool nvalid = (n < N_NODES);
    const int u2 = sub * 2, c0 = sub * 4;

    h2 grn0, grn1, a0, a1;
    {
        const uint2 u = *reinterpret_cast<const uint2*>(&gr[(size_t)(nvalid ? n : 0) * MU + u2]);
        grn0 = bch2(u.x); grn1 = bch2(u.y);
        const uint2 au = *reinterpret_cast<const uint2*>(&atth[u2]);
        a0 = bch2(au.x); a1 = bch2(au.y);
    }
    const h2 hz = {(_Float16)0.f, (_Float16)0.f};
    const h2 hp = {(_Float16)0.2f, (_Float16)0.2f};

    f32x2 acc0 = (f32x2)0.0f, acc1 = (f32x2)0.0f;
    float denom = 0.0f;

    const int beg = nvalid ? row_ptr[n] : 0;
    const int deg = nvalid ? (row_ptr[n + 1] - beg) : 0;

    for (int off = 0; __any(off < deg); off += 16) {
        const int myid = (off + sub < deg) ? esrc[beg + off + sub] : 0;

#define GLD(j) (*reinterpret_cast<const uint2*>(&gl[(size_t)__shfl(myid, (g << 4) + (j)) * MU + u2]))
        uint2 r0 = GLD(0), r1 = GLD(1), r2 = GLD(2), r3 = GLD(3), r4 = GLD(4), r5 = GLD(5);
#pragma unroll
        for (int j = 0; j < 16; ++j) {
            const uint2 nxt = (j + 6 < 16) ? GLD(j + 6) : r0;
            const h2 G0 = bch2(r0.x), G1 = bch2(r0.y);
            const h2 v0 = G0 + grn0, v1 = G1 + grn1;
            const h2 lr0 = __builtin_elementwise_fma(
                __builtin_elementwise_min(v0, hz), hp, __builtin_elementwise_max(v0, hz));
            const h2 lr1 = __builtin_elementwise_fma(
                __builtin_elementwise_min(v1, hz), hp, __builtin_elementwise_max(v1, hz));
            float s = fdot2(lr1, a1, fdot2(lr0, a0, 0.0f));
            s += __shfl_xor(s, 1, 64);
            s += __shfl_xor(s, 2, 64);
            s += __shfl_xor(s, 4, 64);
            s += __shfl_xor(s, 8, 64);
            s = ((off + j) < deg) ? s : -INFINITY;

            const float e1 = fexp2(s);
            denom += e1;
            const f32x2 e2 = {e1, e1};
            const f32x2 gf0 = {(float)G0.x, (float)G0.y};
            const f32x2 gf1 = {(float)G1.x, (float)G1.y};
            acc0 = __builtin_elementwise_fma(gf0, e2, acc0);
            acc1 = __builtin_elementwise_fma(gf1, e2, acc1);
            r0 = r1; r1 = r2; r2 = r3; r3 = r4; r4 = r5; r5 = nxt;
        }
#undef GLD
    }

    if (nvalid) {
        const float inv = 1.0f / (denom + 1e-16f);
        const float4 b4 = *reinterpret_cast<const float4*>(&bias[c0]);
        float4 r;
        r.x = 1.0f / (1.0f + __expf(-(acc0.x * inv + b4.x)));
        r.y = 1.0f / (1.0f + __expf(-(acc0.y * inv + b4.y)));
        r.z = 1.0f / (1.0f + __expf(-(acc1.x * inv + b4.z)));
        r.w = 1.0f / (1.0f + __expf(-(acc1.y * inv + b4.w)));
        *reinterpret_cast<float4*>(&out[(size_t)n * D_OUT + c0]) = r;
    }
}

extern "C" void kernel_launch(void* const* d_in, const int* in_sizes, int n_in,
                              void* d_out, int out_size, void* d_ws, size_t ws_size,
                              hipStream_t stream) {
    const float* x    = (const float*)d_in[0];
    const int*   ei   = (const int*)  d_in[1];
    const float* Wl1  = (const float*)d_in[2];
    const float* bl1  = (const float*)d_in[3];
    const float* Wr1  = (const float*)d_in[4];
    const float* br1  = (const float*)d_in[5];
    const float* att1 = (const float*)d_in[6];
    const float* bi1  = (const float*)d_in[7];
    const float* Wl2  = (const float*)d_in[8];
    const float* bl2  = (const float*)d_in[9];
    const float* Wr2  = (const float*)d_in[10];
    const float* br2  = (const float*)d_in[11];
    const float* att2 = (const float*)d_in[12];
    const float* bi2  = (const float*)d_in[13];
    const float* Wl3  = (const float*)d_in[14];
    const float* bl3  = (const float*)d_in[15];
    const float* Wr3  = (const float*)d_in[16];
    const float* br3  = (const float*)d_in[17];
    const float* att3 = (const float*)d_in[18];
    const float* bi3  = (const float*)d_in[19];

    float* out = (float*)d_out;

    // ---- workspace layout (uints) ----
    unsigned* ws   = (unsigned*)d_ws;
    unsigned* gl16 = ws;                               // N*128
    unsigned* gr16 = gl16 + (size_t)N_NODES * 128;     // N*128
    unsigned* h16  = gr16 + (size_t)N_NODES * 128;     // N*128
    unsigned* gl3  = h16  + (size_t)N_NODES * 128;     // N*32 (fp16 rows, layer 3)
    unsigned* gr3  = gl3  + (size_t)N_NODES * 32;      // N*32
    _Float16* T1l  = (_Float16*)(gr3 + (size_t)N_NODES * 32); // 32768 f16
    _Float16* T1r  = T1l + 32768;
    _Float16* T2l  = T1r + 32768;                      // 65536 f16
    _Float16* T2r  = T2l + 65536;
    _Float16* T3l  = T2r + 65536;                      // 16384 f16
    _Float16* T3r  = T3l + 16384;
    unsigned* ath1 = (unsigned*)(T3r + 16384);         // 128
    unsigned* ath2 = ath1 + 128;
    unsigned* ath3 = ath2 + 128;                       // 32
    int* deg     = (int*)(ath3 + 32);                  // N
    int* row_ptr = deg + N_NODES;                      // N+1
    int* cursor  = row_ptr + N_NODES + 1;              // N
    int* esrc    = cursor + N_NODES;                   // E

    // ---- prep: zero deg; conversions + W transpose + degree count; CSR ----
    zero_deg<<<(N_NODES + 255) / 256, 256, 0, stream>>>(deg);
    prep_all<<<59 + (N_EDGES + 255) / 256, 256, 0, stream>>>(
        att1, ath1, att2, ath2, att3, ath3,
        Wl1, Wr1, Wl2, Wr2, Wl3, Wr3,
        T1l, T1r, T2l, T2r, T3l, T3r,
        ei, deg);
    scan_rowptr<<<1, 1024, 0, stream>>>(deg, row_ptr, cursor);
    scatter_edges<<<(N_EDGES + 255) / 256, 256, 0, stream>>>(ei, cursor, esrc);

    const int RT64 = (N_NODES + 63) / 64;              // 157

    // ---- Layer 1: 128 -> 8x32, elu (A read as fp32 directly) ----
    gemm_dual_mfma<D_IN, true, true><<<dim3(RT64, 4), 256, 0, stream>>>(
        x, T1l, bl1, T1r, br1, gl16, gr16, D2, N_NODES);
    gat_wave_h2<<<(N_NODES + 3) / 4, 256, 0, stream>>>(
        row_ptr, esrc, gl16, gr16, ath1, bi1, h16);

    // ---- Layer 2: 256 -> 8x32, elu ----
    gemm_dual_mfma<D2, true, false><<<dim3(RT64, 4), 256, 0, stream>>>(
        h16, T2l, bl2, T2r, br2, gl16, gr16, D2, N_NODES);
    gat_wave_h2<<<(N_NODES + 3) / 4, 256, 0, stream>>>(
        row_ptr, esrc, gl16, gr16, ath2, bi2, h16);

    // ---- Layer 3: 256 -> 64, 1 head, sigmoid (fp16 rows) ----
    gemm_dual_mfma<D2, true, false><<<dim3(RT64, 1), 256, 0, stream>>>(
        h16, T3l, bl3, T3r, br3, gl3, gr3, D_OUT, N_NODES);
    gat_group3h<<<(N_NODES + 15) / 16, 256, 0, stream>>>(
        row_ptr, esrc, gl3, gr3, ath3, bi3, out);
}